// Round 3
// baseline (678.516 us; speedup 1.0000x reference)
//
#include <hip/hip_runtime.h>
#include <math.h>

// Problem constants: B=8, planes=4, Cin=64, Cout=128, H=W=64, K=3,S=1,D=1,P=1
#define CIN   64
#define COUT  128
#define HW    4096
#define EPSF  1e-6f
#define LOG_EPS -13.815510557964274f   // logf(1e-6)
#define BLK   512

// ---------------- prep: w1n [576], w2n [8192] into ws (kept identical to R1 — bit-stable) ----------------
__global__ void prep_weights(const float* __restrict__ w1x, const float* __restrict__ w1y,
                             const float* __restrict__ w2x, const float* __restrict__ w2y,
                             float* __restrict__ wsn) {
  __shared__ float red[256];
  const int tid = threadIdx.x;
  float s1 = 0.f, s2 = 0.f;
  for (int i = tid; i < 576; i += 256)  { float v = w1x[i] + w1y[i]; s1 += v * v; }
  for (int i = tid; i < 8192; i += 256) { float v = w2x[i] + w2y[i]; s2 += v * v; }
  red[tid] = s1; __syncthreads();
  for (int s = 128; s > 0; s >>= 1) { if (tid < s) red[tid] += red[tid + s]; __syncthreads(); }
  const float t1 = red[0]; __syncthreads();
  red[tid] = s2; __syncthreads();
  for (int s = 128; s > 0; s >>= 1) { if (tid < s) red[tid] += red[tid + s]; __syncthreads(); }
  const float t2 = red[0];
  const float r1 = 1.0f / t1, r2 = 1.0f / t2;
  for (int i = tid; i < 576; i += 256)  { float v = w1x[i] + w1y[i]; wsn[i]       = v * v * r1; }
  for (int i = tid; i < 8192; i += 256) { float v = w2x[i] + w2y[i]; wsn[576 + i] = v * v * r2; }
}

// ---------------- fused depthwise(3x3)+pointwise(1x1), register-prefetch pipelined ----------------
// grid: 512 blocks = (b*4+plane)[32] x row-tile[16, 4 rows]; block 512 thr; 2 barriers/chunk.
// Key facts: left/right halo cols are ALWAYS the pad constant (image W==64, P==1), so LDS
// stores only the 64 real cols per row -> staging is 3 coalesced float4 loads/thread.
__global__ __launch_bounds__(BLK, 4) void fused_conv(
    const float* __restrict__ x,
    const float* __restrict__ w1x, const float* __restrict__ w1y,
    const float* __restrict__ w2x, const float* __restrict__ w2y,
    const float* __restrict__ wsn,   // [0..575]=w1n, [576..8767]=w2n
    float* __restrict__ out) {
  const int tid   = threadIdx.x;
  const int rt    = blockIdx.x & 15;
  const int bp    = blockIdx.x >> 4;
  const int plane = bp & 3;
  const bool is_abs = (plane == 1);
  const float PAD = is_abs ? LOG_EPS : 0.f;
  const float* w1 = (plane < 2) ? wsn         : (plane == 2 ? w1x : w1y);
  const float* w2 = (plane < 2) ? (wsn + 576) : (plane == 2 ? w2x : w2y);

  // LDS 53.5 KB -> 2 blocks/CU (107 KB of 160). xs row stride 68 -> phase-B b128 reads are 2-way (free).
  __shared__ float xs[16][6][68];   // 16 ch x 6 rows x 64 real cols (+4 pad)
  __shared__ float ts[16][260];     // depthwise result: 16 ch x 256 px (+4 pad)
  __shared__ float w2s[16][132];    // w2 chunk transposed [c][o] (+4 pad)
  __shared__ float w1s[576];

  for (int i = tid; i < 576; i += BLK) w1s[i] = w1[i];

  const float* xbase = x + (size_t)bp * CIN * HW;

  // ---- staging index precompute: j=0..2 covers 96 rows x 16 quads = 1536 float4 slots ----
  int sc[3], srr[3], sgr[3]; bool sv[3];
  #pragma unroll
  for (int j = 0; j < 3; ++j) {
    int s   = tid + BLK * j;
    int row = s >> 4;              // 0..95
    int c   = row / 6;             // 0..15 (magic div)
    int rr  = row - 6 * c;         // 0..5
    int gr  = rt * 4 + rr - 1;     // image row, may be -1/64 at edge tiles
    sc[j] = c; srr[j] = rr;
    sgr[j] = gr < 0 ? 0 : (gr > 63 ? 63 : gr);   // clamped (safe) address
    sv[j]  = ((unsigned)gr < 64u);
  }
  const int sq = (tid & 15) * 4;   // col quad
  const int wo = tid >> 2;         // 0..127 output row of w2
  const int wq = tid & 3;          // c-quad within 16-ch chunk

  // ---- prologue: stage chunk 0 ----
  {
    #pragma unroll
    for (int j = 0; j < 3; ++j) {
      float4 v = *(const float4*)(xbase + (size_t)sc[j] * HW + sgr[j] * 64 + sq);
      if (is_abs) { v.x = logf(v.x + EPSF); v.y = logf(v.y + EPSF);
                    v.z = logf(v.z + EPSF); v.w = logf(v.w + EPSF); }
      if (!sv[j]) v = make_float4(PAD, PAD, PAD, PAD);
      *(float4*)&xs[sc[j]][srr[j]][sq] = v;
    }
    float4 wv4 = *(const float4*)(w2 + wo * CIN + wq * 4);
    w2s[wq*4+0][wo] = wv4.x; w2s[wq*4+1][wo] = wv4.y;
    w2s[wq*4+2][wo] = wv4.z; w2s[wq*4+3][wo] = wv4.w;
  }
  __syncthreads();

  // ---- per-phase lane mappings ----
  const int og  = tid >> 6;          // wave id 0..7
  const int o0  = og * 16;           // 16 outputs per wave
  const int p0c = (tid & 63) * 4;    // 4 px per lane (phase C)
  const int bc   = tid >> 5;         // phase B channel 0..15
  const int bl   = tid & 31;
  const int bp0  = bl * 8;           // 8 px per lane (phase B)
  const int bri  = bp0 >> 6;         // tile row 0..3
  const int bcol = bp0 & 63;         // col 0..56 step 8

  float acc[64];
  #pragma unroll
  for (int j = 0; j < 64; ++j) acc[j] = 0.f;

  #pragma unroll 1
  for (int cc = 0; cc < 4; ++cc) {
    // ---- issue next-chunk prefetch (latency hides under phase B + C) ----
    float4 nx[3]; float4 nw;
    if (cc < 3) {
      #pragma unroll
      for (int j = 0; j < 3; ++j)
        nx[j] = *(const float4*)(xbase + (size_t)((cc+1)*16 + sc[j]) * HW + sgr[j] * 64 + sq);
      nw = *(const float4*)(w2 + wo * CIN + (cc+1)*16 + wq * 4);
    }

    // ---- phase B: depthwise 3x3 -> ts ----
    {
      float wv[9];
      #pragma unroll
      for (int k2 = 0; k2 < 9; ++k2) wv[k2] = w1s[(cc*16 + bc)*9 + k2];
      float at[8];
      #pragma unroll
      for (int pp = 0; pp < 8; ++pp) at[pp] = 0.f;
      #pragma unroll
      for (int kr = 0; kr < 3; ++kr) {
        const float* xr = &xs[bc][bri + kr][0];
        float xv[10];
        { int il = bcol ? bcol - 1 : 0;       float lv = xr[il]; xv[0] = bcol ? lv : PAD; }
        float4 a0 = *(const float4*)(xr + bcol);
        float4 a1 = *(const float4*)(xr + bcol + 4);
        xv[1]=a0.x; xv[2]=a0.y; xv[3]=a0.z; xv[4]=a0.w;
        xv[5]=a1.x; xv[6]=a1.y; xv[7]=a1.z; xv[8]=a1.w;
        { int ir = (bcol==56) ? bcol + 7 : bcol + 8; float rv = xr[ir]; xv[9] = (bcol==56) ? PAD : rv; }
        #pragma unroll
        for (int pp = 0; pp < 8; ++pp) {
          at[pp] += xv[pp]     * wv[kr*3 + 0];
          at[pp] += xv[pp + 1] * wv[kr*3 + 1];
          at[pp] += xv[pp + 2] * wv[kr*3 + 2];
        }
      }
      *(float4*)&ts[bc][bp0]     = make_float4(at[0], at[1], at[2], at[3]);
      *(float4*)&ts[bc][bp0 + 4] = make_float4(at[4], at[5], at[6], at[7]);
    }
    __syncthreads();   // bar1: ts ready, xs fully consumed

    // ---- commit prefetched x -> xs (xs not read by phase C; next B ordered by bar2) ----
    if (cc < 3) {
      #pragma unroll
      for (int j = 0; j < 3; ++j) {
        float4 v = nx[j];
        if (is_abs) { v.x = logf(v.x + EPSF); v.y = logf(v.y + EPSF);
                      v.z = logf(v.z + EPSF); v.w = logf(v.w + EPSF); }
        if (!sv[j]) v = make_float4(PAD, PAD, PAD, PAD);
        *(float4*)&xs[sc[j]][srr[j]][sq] = v;
      }
    }

    // ---- phase C: pointwise GEMM accumulate ----
    #pragma unroll
    for (int k = 0; k < 16; ++k) {
      float4 tq  = *(const float4*)&ts[k][p0c];      // 1KB/wave contiguous, conflict-free
      float4 wq0 = *(const float4*)&w2s[k][o0];      // wave-broadcast
      float4 wq1 = *(const float4*)&w2s[k][o0 + 4];
      float4 wq2 = *(const float4*)&w2s[k][o0 + 8];
      float4 wq3 = *(const float4*)&w2s[k][o0 + 12];
      const float wvals[16] = {wq0.x, wq0.y, wq0.z, wq0.w, wq1.x, wq1.y, wq1.z, wq1.w,
                               wq2.x, wq2.y, wq2.z, wq2.w, wq3.x, wq3.y, wq3.z, wq3.w};
      #pragma unroll
      for (int jj = 0; jj < 16; ++jj) {
        const float w = wvals[jj];
        acc[jj*4 + 0] += w * tq.x;
        acc[jj*4 + 1] += w * tq.y;
        acc[jj*4 + 2] += w * tq.z;
        acc[jj*4 + 3] += w * tq.w;
      }
    }
    __syncthreads();   // bar2: ts & w2s consumed

    // ---- commit prefetched w2 -> w2s (ordered before C(cc+1) by next bar1) ----
    if (cc < 3) {
      w2s[wq*4+0][wo] = nw.x; w2s[wq*4+1][wo] = nw.y;
      w2s[wq*4+2][wo] = nw.z; w2s[wq*4+3][wo] = nw.w;
    }
  }

  // ---- epilogue: (optional exp) + coalesced float4 stores ----
  float* obase = out + (size_t)bp * COUT * HW + rt * 256 + p0c;
  #pragma unroll
  for (int jj = 0; jj < 16; ++jj) {
    float4 v = make_float4(acc[jj*4], acc[jj*4+1], acc[jj*4+2], acc[jj*4+3]);
    if (is_abs) { v.x = expf(v.x); v.y = expf(v.y); v.z = expf(v.z); v.w = expf(v.w); }
    *(float4*)(obase + (size_t)(o0 + jj) * HW) = v;
  }
}

extern "C" void kernel_launch(void* const* d_in, const int* in_sizes, int n_in,
                              void* d_out, int out_size, void* d_ws, size_t ws_size,
                              hipStream_t stream) {
  const float* x   = (const float*)d_in[0];
  const float* w1x = (const float*)d_in[1];
  const float* w1y = (const float*)d_in[2];
  const float* w2x = (const float*)d_in[3];
  const float* w2y = (const float*)d_in[4];
  float* out = (float*)d_out;
  float* wsn = (float*)d_ws;   // 8768 floats

  prep_weights<<<1, 256, 0, stream>>>(w1x, w1y, w2x, w2y, wsn);
  fused_conv<<<512, BLK, 0, stream>>>(x, w1x, w1y, w2x, w2y, wsn, out);
}

// Round 4
// 367.117 us; speedup vs baseline: 1.8482x; 1.8482x over previous
//
#include <hip/hip_runtime.h>
#include <math.h>

// Problem constants: B=8, planes=4, Cin=64, Cout=128, H=W=64, K=3,S=1,D=1,P=1
#define CIN   64
#define COUT  128
#define HW    4096
#define EPSF  1e-6f
#define LOG_EPS -13.815510557964274f   // logf(1e-6)
#define BLK   512

// ---------------- prep: w1n [576], w2n [8192] into ws ----------------
__global__ void prep_weights(const float* __restrict__ w1x, const float* __restrict__ w1y,
                             const float* __restrict__ w2x, const float* __restrict__ w2y,
                             float* __restrict__ wsn) {
  __shared__ float red[256];
  const int tid = threadIdx.x;
  float s1 = 0.f, s2 = 0.f;
  for (int i = tid; i < 576; i += 256)  { float v = w1x[i] + w1y[i]; s1 += v * v; }
  for (int i = tid; i < 8192; i += 256) { float v = w2x[i] + w2y[i]; s2 += v * v; }
  red[tid] = s1; __syncthreads();
  for (int s = 128; s > 0; s >>= 1) { if (tid < s) red[tid] += red[tid + s]; __syncthreads(); }
  const float t1 = red[0]; __syncthreads();
  red[tid] = s2; __syncthreads();
  for (int s = 128; s > 0; s >>= 1) { if (tid < s) red[tid] += red[tid + s]; __syncthreads(); }
  const float t2 = red[0];
  const float r1 = 1.0f / t1, r2 = 1.0f / t2;
  for (int i = tid; i < 576; i += 256)  { float v = w1x[i] + w1y[i]; wsn[i]       = v * v * r1; }
  for (int i = tid; i < 8192; i += 256) { float v = w2x[i] + w2y[i]; wsn[576 + i] = v * v * r2; }
}

// ---------------- fused depthwise(3x3)+pointwise(1x1), register-prefetch pipelined ----------------
// grid: 512 blocks = (b*4+plane)[32] x row-tile[16, 4 rows]; block 512 thr; 2 barriers/chunk.
// __launch_bounds__(512,2): VGPR cap 256 — R3's (512,4)=128 cap forced a catastrophic scratch
// spill (FETCH 26->673MB, WRITE 68MB->1.35GB, VALUBusy 4%). Scratch is never worth occupancy.
__global__ __launch_bounds__(BLK, 2) void fused_conv(
    const float* __restrict__ x,
    const float* __restrict__ w1x, const float* __restrict__ w1y,
    const float* __restrict__ w2x, const float* __restrict__ w2y,
    const float* __restrict__ wsn,   // [0..575]=w1n, [576..8767]=w2n
    float* __restrict__ out) {
  const int tid   = threadIdx.x;
  const int rt    = blockIdx.x & 15;
  const int bp    = blockIdx.x >> 4;
  const int plane = bp & 3;
  const bool is_abs = (plane == 1);
  const float PAD = is_abs ? LOG_EPS : 0.f;
  const float* w1 = (plane < 2) ? wsn         : (plane == 2 ? w1x : w1y);
  const float* w2 = (plane < 2) ? (wsn + 576) : (plane == 2 ? w2x : w2y);

  // LDS 53.5 KB. xs row stride 68 -> phase-B b128 reads spread banks (2-way = free).
  __shared__ float xs[16][6][68];   // 16 ch x 6 rows x 64 real cols (+4 pad)
  __shared__ float ts[16][260];     // depthwise result: 16 ch x 256 px (+4 pad)
  __shared__ float w2s[16][132];    // w2 chunk transposed [c][o] (+4 pad)
  __shared__ float w1s[576];

  for (int i = tid; i < 576; i += BLK) w1s[i] = w1[i];

  const float* xbase = x + (size_t)bp * CIN * HW;

  // staging indices: j=0..2 covers 96 rows x 16 quads = 1536 float4 slots
  int sc[3], srr[3], sgr[3]; bool sv[3];
  #pragma unroll
  for (int j = 0; j < 3; ++j) {
    int s   = tid + BLK * j;
    int row = s >> 4;              // 0..95
    int c   = row / 6;             // 0..15
    int rr  = row - 6 * c;         // 0..5
    int gr  = rt * 4 + rr - 1;
    sc[j] = c; srr[j] = rr;
    sgr[j] = gr < 0 ? 0 : (gr > 63 ? 63 : gr);   // clamped (safe) address
    sv[j]  = ((unsigned)gr < 64u);
  }
  const int sq = (tid & 15) * 4;   // col quad
  const int wo = tid >> 2;         // 0..127 output row of w2
  const int wq = tid & 3;          // c-quad within 16-ch chunk

  // ---- prologue: stage chunk 0 ----
  {
    #pragma unroll
    for (int j = 0; j < 3; ++j) {
      float4 v = *(const float4*)(xbase + (size_t)sc[j] * HW + sgr[j] * 64 + sq);
      if (is_abs) { v.x = logf(v.x + EPSF); v.y = logf(v.y + EPSF);
                    v.z = logf(v.z + EPSF); v.w = logf(v.w + EPSF); }
      if (!sv[j]) v = make_float4(PAD, PAD, PAD, PAD);
      *(float4*)&xs[sc[j]][srr[j]][sq] = v;
    }
    float4 wv4 = *(const float4*)(w2 + wo * CIN + wq * 4);
    w2s[wq*4+0][wo] = wv4.x; w2s[wq*4+1][wo] = wv4.y;
    w2s[wq*4+2][wo] = wv4.z; w2s[wq*4+3][wo] = wv4.w;
  }
  __syncthreads();

  // per-phase lane mappings
  const int og  = tid >> 6;          // wave id 0..7
  const int o0  = og * 16;           // 16 outputs per wave
  const int p0c = (tid & 63) * 4;    // 4 px per lane (phase C)
  const int bc   = tid >> 5;         // phase B channel 0..15
  const int bl   = tid & 31;
  const int bp0  = bl * 8;           // 8 px per lane (phase B)
  const int bri  = bp0 >> 6;         // tile row 0..3
  const int bcol = bp0 & 63;         // col 0..56 step 8

  float acc[64];
  #pragma unroll
  for (int j = 0; j < 64; ++j) acc[j] = 0.f;

  for (int cc = 0; cc < 4; ++cc) {   // compiler may fully unroll (all indices static)
    // ---- issue next-chunk prefetch (latency hides under phase B + C) ----
    float4 nx[3]; float4 nw;
    if (cc < 3) {
      #pragma unroll
      for (int j = 0; j < 3; ++j)
        nx[j] = *(const float4*)(xbase + (size_t)((cc+1)*16 + sc[j]) * HW + sgr[j] * 64 + sq);
      nw = *(const float4*)(w2 + wo * CIN + (cc+1)*16 + wq * 4);
    }

    // ---- phase B: depthwise 3x3 -> ts ----
    {
      float wv[9];
      #pragma unroll
      for (int k2 = 0; k2 < 9; ++k2) wv[k2] = w1s[(cc*16 + bc)*9 + k2];
      float at[8];
      #pragma unroll
      for (int pp = 0; pp < 8; ++pp) at[pp] = 0.f;
      #pragma unroll
      for (int kr = 0; kr < 3; ++kr) {
        const float* xr = &xs[bc][bri + kr][0];
        float xv[10];
        { int il = bcol ? bcol - 1 : 0;       float lv = xr[il]; xv[0] = bcol ? lv : PAD; }
        float4 a0 = *(const float4*)(xr + bcol);
        float4 a1 = *(const float4*)(xr + bcol + 4);
        xv[1]=a0.x; xv[2]=a0.y; xv[3]=a0.z; xv[4]=a0.w;
        xv[5]=a1.x; xv[6]=a1.y; xv[7]=a1.z; xv[8]=a1.w;
        { int ir = (bcol==56) ? bcol + 7 : bcol + 8; float rv = xr[ir]; xv[9] = (bcol==56) ? PAD : rv; }
        #pragma unroll
        for (int pp = 0; pp < 8; ++pp) {
          at[pp] += xv[pp]     * wv[kr*3 + 0];
          at[pp] += xv[pp + 1] * wv[kr*3 + 1];
          at[pp] += xv[pp + 2] * wv[kr*3 + 2];
        }
      }
      *(float4*)&ts[bc][bp0]     = make_float4(at[0], at[1], at[2], at[3]);
      *(float4*)&ts[bc][bp0 + 4] = make_float4(at[4], at[5], at[6], at[7]);
    }
    __syncthreads();   // bar1: ts ready, xs fully consumed

    // ---- commit prefetched x -> xs (xs not read by phase C) ----
    if (cc < 3) {
      #pragma unroll
      for (int j = 0; j < 3; ++j) {
        float4 v = nx[j];
        if (is_abs) { v.x = logf(v.x + EPSF); v.y = logf(v.y + EPSF);
                      v.z = logf(v.z + EPSF); v.w = logf(v.w + EPSF); }
        if (!sv[j]) v = make_float4(PAD, PAD, PAD, PAD);
        *(float4*)&xs[sc[j]][srr[j]][sq] = v;
      }
    }

    // ---- phase C: pointwise GEMM accumulate (w2 read 4-wide to cap live regs) ----
    #pragma unroll
    for (int k = 0; k < 16; ++k) {
      float4 tq = *(const float4*)&ts[k][p0c];       // 1KB/wave contiguous, conflict-free
      #pragma unroll
      for (int g = 0; g < 4; ++g) {
        float4 wv4 = *(const float4*)&w2s[k][o0 + g*4];   // wave-broadcast
        acc[(g*4+0)*4+0] += wv4.x*tq.x; acc[(g*4+0)*4+1] += wv4.x*tq.y;
        acc[(g*4+0)*4+2] += wv4.x*tq.z; acc[(g*4+0)*4+3] += wv4.x*tq.w;
        acc[(g*4+1)*4+0] += wv4.y*tq.x; acc[(g*4+1)*4+1] += wv4.y*tq.y;
        acc[(g*4+1)*4+2] += wv4.y*tq.z; acc[(g*4+1)*4+3] += wv4.y*tq.w;
        acc[(g*4+2)*4+0] += wv4.z*tq.x; acc[(g*4+2)*4+1] += wv4.z*tq.y;
        acc[(g*4+2)*4+2] += wv4.z*tq.z; acc[(g*4+2)*4+3] += wv4.z*tq.w;
        acc[(g*4+3)*4+0] += wv4.w*tq.x; acc[(g*4+3)*4+1] += wv4.w*tq.y;
        acc[(g*4+3)*4+2] += wv4.w*tq.z; acc[(g*4+3)*4+3] += wv4.w*tq.w;
      }
    }
    __syncthreads();   // bar2: ts & w2s consumed

    // ---- commit prefetched w2 -> w2s ----
    if (cc < 3) {
      w2s[wq*4+0][wo] = nw.x; w2s[wq*4+1][wo] = nw.y;
      w2s[wq*4+2][wo] = nw.z; w2s[wq*4+3][wo] = nw.w;
    }
  }

  // ---- epilogue: (optional exp) + coalesced float4 stores ----
  float* obase = out + (size_t)bp * COUT * HW + rt * 256 + p0c;
  #pragma unroll
  for (int jj = 0; jj < 16; ++jj) {
    float4 v = make_float4(acc[jj*4], acc[jj*4+1], acc[jj*4+2], acc[jj*4+3]);
    if (is_abs) { v.x = expf(v.x); v.y = expf(v.y); v.z = expf(v.z); v.w = expf(v.w); }
    *(float4*)(obase + (size_t)(o0 + jj) * HW) = v;
  }
}

extern "C" void kernel_launch(void* const* d_in, const int* in_sizes, int n_in,
                              void* d_out, int out_size, void* d_ws, size_t ws_size,
                              hipStream_t stream) {
  const float* x   = (const float*)d_in[0];
  const float* w1x = (const float*)d_in[1];
  const float* w1y = (const float*)d_in[2];
  const float* w2x = (const float*)d_in[3];
  const float* w2y = (const float*)d_in[4];
  float* out = (float*)d_out;
  float* wsn = (float*)d_ws;   // 8768 floats

  prep_weights<<<1, 256, 0, stream>>>(w1x, w1y, w2x, w2y, wsn);
  fused_conv<<<512, BLK, 0, stream>>>(x, w1x, w1y, w2x, w2y, wsn, out);
}

// Round 5
// 174.552 us; speedup vs baseline: 3.8872x; 2.1032x over previous
//
#include <hip/hip_runtime.h>
#include <math.h>

// Problem constants: B=8, planes=4, Cin=64, Cout=128, H=W=64, K=3,S=1,D=1,P=1
#define CIN   64
#define COUT  128
#define HW    4096
#define EPSF  1e-6f
#define LOG_EPS -13.815510557964274f   // logf(1e-6)
#define BLK   512

#define LDSP(p) ((__attribute__((address_space(3))) void*)(p))
#define GLBP(p) ((const __attribute__((address_space(1))) void*)(p))

// ---------------- prep: w1n [576], w2n [8192] into ws (bit-stable vs R1) ----------------
__global__ void prep_weights(const float* __restrict__ w1x, const float* __restrict__ w1y,
                             const float* __restrict__ w2x, const float* __restrict__ w2y,
                             float* __restrict__ wsn) {
  __shared__ float red[256];
  const int tid = threadIdx.x;
  float s1 = 0.f, s2 = 0.f;
  for (int i = tid; i < 576; i += 256)  { float v = w1x[i] + w1y[i]; s1 += v * v; }
  for (int i = tid; i < 8192; i += 256) { float v = w2x[i] + w2y[i]; s2 += v * v; }
  red[tid] = s1; __syncthreads();
  for (int s = 128; s > 0; s >>= 1) { if (tid < s) red[tid] += red[tid + s]; __syncthreads(); }
  const float t1 = red[0]; __syncthreads();
  red[tid] = s2; __syncthreads();
  for (int s = 128; s > 0; s >>= 1) { if (tid < s) red[tid] += red[tid + s]; __syncthreads(); }
  const float t2 = red[0];
  const float r1 = 1.0f / t1, r2 = 1.0f / t2;
  for (int i = tid; i < 576; i += 256)  { float v = w1x[i] + w1y[i]; wsn[i]       = v * v * r1; }
  for (int i = tid; i < 8192; i += 256) { float v = w2x[i] + w2y[i]; wsn[576 + i] = v * v * r2; }
}

// ---------------- fused depthwise(3x3)+pointwise(1x1), async global_load_lds pipeline ----------------
// R3/R4 lesson: register-held prefetch spills to scratch (FETCH 26->370MB, WRITE 68->745MB).
// Fix: global_load_lds (zero-VGPR DMA) + double-buffered xs + raw s_barrier with explicit
// vmcnt/lgkmcnt so staging loads stay in flight across a full phase-B+C window.
// xs is stride-64 (linear DMA dest) with XOR swizzle (byte bits 5-7 ^= row&7) applied to BOTH
// the per-lane global source address and every phase-B LDS read (rule #21: both-sides-or-neither).
__global__ __launch_bounds__(BLK, 2) void fused_conv(
    const float* __restrict__ x,
    const float* __restrict__ w1x, const float* __restrict__ w1y,
    const float* __restrict__ w2x, const float* __restrict__ w2y,
    const float* __restrict__ wsn,   // [0..575]=w1n, [576..8767]=w2n
    float* __restrict__ out) {
  const int tid   = threadIdx.x;
  const int rt    = blockIdx.x & 15;   // row tile: rows rt*4 .. rt*4+3
  const int bp    = blockIdx.x >> 4;   // b*4 + plane
  const int plane = bp & 3;
  const bool is_abs = (plane == 1);
  const float PAD = is_abs ? LOG_EPS : 0.f;
  const float* w1 = (plane < 2) ? wsn         : (plane == 2 ? w1x : w1y);
  const float* w2 = (plane < 2) ? (wsn + 576) : (plane == 2 ? w2x : w2y);

  // LDS ~102 KB -> 1 block/CU.
  __shared__ float xs[2][16 * 6 * 64];  // 2 x 24KB chunk buffers, SWIZZLED stride-64 layout
  __shared__ float ts[16][260];         // depthwise result (padded, conflict-balanced)
  __shared__ float w2s[64][132];        // FULL w2 transposed [c][o], staged once
  __shared__ float w1s[576];

  const int wav = tid >> 6;
  const int lan = tid & 63;

  // ---- per-thread DMA constants: 3 issues/wave, seg s = wav*3+j covers LDS floats [s*256, s*256+256) ----
  int gch[3], goff[3]; unsigned lbase[3];
  #pragma unroll
  for (int j = 0; j < 3; ++j) {
    int s     = wav * 3 + j;
    int row16 = s * 4 + (lan >> 4);          // 0..95 = ch*6 + rr
    int ch    = row16 / 6;
    int rr    = row16 - 6 * ch;
    int gr    = rt * 4 + rr - 1;
    int grc   = gr < 0 ? 0 : (gr > 63 ? 63 : gr);       // clamped (safe) row
    int colf  = (((lan & 15) * 16) ^ ((row16 & 7) << 5)) >> 2;  // swizzled source col
    gch[j]  = ch;
    goff[j] = grc * 64 + colf;
    lbase[j] = (unsigned)(s * 1024);         // wave-uniform LDS byte base of the segment
  }
  // ---- per-lane fixup partition: wave w owns floats [w*768, w*768+768), lane owns 12 ----
  const int fbase = wav * 768 + lan * 12;
  unsigned vmask = 0;
  #pragma unroll
  for (int i = 0; i < 12; ++i) {
    int row16 = (fbase + i) >> 6;
    int rr    = row16 % 6;
    int gr    = rt * 4 + rr - 1;
    if ((unsigned)gr < 64u) vmask |= (1u << i);
  }
  const bool tile_edge = (rt == 0) | (rt == 15);

  const float* xbase = x + (size_t)bp * CIN * HW;

  // ---- prologue: issue chunk-0 DMA, then (overlapped) stage w1s + full w2s ----
  {
    float* Xn = &xs[0][0];
    #pragma unroll
    for (int j = 0; j < 3; ++j)
      __builtin_amdgcn_global_load_lds(GLBP(xbase + (size_t)gch[j] * HW + goff[j]),
                                       LDSP((char*)Xn + lbase[j]), 16, 0, 0);
  }
  for (int i = tid; i < 576; i += BLK) w1s[i] = w1[i];
  {
    const int wo = tid >> 2, wq = tid & 3;   // 128 o's x 4 threads, 16 c's each
    #pragma unroll
    for (int q = 0; q < 4; ++q) {
      int c0 = wq * 4 + q * 16;
      float4 v = *(const float4*)(w2 + wo * CIN + c0);
      w2s[c0 + 0][wo] = v.x; w2s[c0 + 1][wo] = v.y;
      w2s[c0 + 2][wo] = v.z; w2s[c0 + 3][wo] = v.w;
    }
  }

  // ---- per-phase lane mappings ----
  const int og  = tid >> 6;          // wave id
  const int o0  = og * 16;           // 16 outputs per wave
  const int p0c = (tid & 63) * 4;    // 4 px per lane (phase C)
  const int bc   = tid >> 5;         // phase B channel 0..15
  const int bl   = tid & 31;
  const int bp0  = bl * 8;           // 8 px per lane (phase B)
  const int bri  = bp0 >> 6;         // tile row 0..3
  const int bcol = bp0 & 63;         // col 0..56 step 8

  float acc[64];
  #pragma unroll
  for (int j = 0; j < 64; ++j) acc[j] = 0.f;

  #pragma unroll 1
  for (int cc = 0; cc < 4; ++cc) {
    float* Xb = &xs[cc & 1][0];

    // ---- staging wait + per-wave fixup (own segments only) + barrier ----
    asm volatile("s_waitcnt vmcnt(0)" ::: "memory");
    if (is_abs) {
      #pragma unroll
      for (int q = 0; q < 3; ++q) {
        float4 v = *(float4*)&Xb[fbase + q * 4];
        v.x = (vmask >> (q*4+0) & 1u) ? logf(v.x + EPSF) : LOG_EPS;
        v.y = (vmask >> (q*4+1) & 1u) ? logf(v.y + EPSF) : LOG_EPS;
        v.z = (vmask >> (q*4+2) & 1u) ? logf(v.z + EPSF) : LOG_EPS;
        v.w = (vmask >> (q*4+3) & 1u) ? logf(v.w + EPSF) : LOG_EPS;
        *(float4*)&Xb[fbase + q * 4] = v;
      }
    } else if (tile_edge) {
      #pragma unroll
      for (int i = 0; i < 12; ++i)
        if (!(vmask >> i & 1u)) Xb[fbase + i] = 0.f;
    }
    asm volatile("s_waitcnt lgkmcnt(0)" ::: "memory");
    __builtin_amdgcn_s_barrier();            // chunk cc ready (also w1s/w2s on first iter)
    __builtin_amdgcn_sched_barrier(0);

    // ---- issue next-chunk DMA into the other buffer (in flight across B + C) ----
    if (cc < 3) {
      float* Xn = &xs[(cc & 1) ^ 1][0];
      #pragma unroll
      for (int j = 0; j < 3; ++j)
        __builtin_amdgcn_global_load_lds(GLBP(xbase + (size_t)((cc + 1) * 16 + gch[j]) * HW + goff[j]),
                                         LDSP((char*)Xn + lbase[j]), 16, 0, 0);
    }

    // ---- phase B: depthwise 3x3 -> ts (swizzled reads) ----
    {
      float wv[9];
      #pragma unroll
      for (int k2 = 0; k2 < 9; ++k2) wv[k2] = w1s[(cc * 16 + bc) * 9 + k2];
      float at[8];
      #pragma unroll
      for (int pp = 0; pp < 8; ++pp) at[pp] = 0.f;
      #pragma unroll
      for (int kr = 0; kr < 3; ++kr) {
        const int row16 = bc * 6 + bri + kr;
        const float* xr = Xb + row16 * 64;
        const int swzf  = (row16 & 7) << 3;        // float-index XOR (byte bits 5-7)
        float xv[10];
        { int il = bcol ? bcol - 1 : 0; float lv = xr[il ^ swzf]; xv[0] = bcol ? lv : PAD; }
        const int c0 = bcol ^ swzf;                // bcol is 8-aligned: granule-safe
        float4 a0 = *(const float4*)(xr + c0);
        float4 a1 = *(const float4*)(xr + c0 + 4);
        xv[1] = a0.x; xv[2] = a0.y; xv[3] = a0.z; xv[4] = a0.w;
        xv[5] = a1.x; xv[6] = a1.y; xv[7] = a1.z; xv[8] = a1.w;
        { int ir = (bcol == 56) ? 63 : bcol + 8; float rv = xr[ir ^ swzf]; xv[9] = (bcol == 56) ? PAD : rv; }
        #pragma unroll
        for (int pp = 0; pp < 8; ++pp) {
          at[pp] += xv[pp]     * wv[kr * 3 + 0];
          at[pp] += xv[pp + 1] * wv[kr * 3 + 1];
          at[pp] += xv[pp + 2] * wv[kr * 3 + 2];
        }
      }
      *(float4*)&ts[bc][bp0]     = make_float4(at[0], at[1], at[2], at[3]);
      *(float4*)&ts[bc][bp0 + 4] = make_float4(at[4], at[5], at[6], at[7]);
    }
    asm volatile("s_waitcnt lgkmcnt(0)" ::: "memory");
    __builtin_amdgcn_s_barrier();            // bar1: ts ready (DMA still in flight - no vmcnt here)
    __builtin_amdgcn_sched_barrier(0);

    // ---- phase C: pointwise GEMM accumulate ----
    #pragma unroll
    for (int k = 0; k < 16; ++k) {
      float4 tq = *(const float4*)&ts[k][p0c];            // contiguous, conflict-balanced
      #pragma unroll
      for (int g = 0; g < 4; ++g) {
        float4 wv4 = *(const float4*)&w2s[cc * 16 + k][o0 + g * 4];   // wave-broadcast
        acc[(g*4+0)*4+0] += wv4.x*tq.x; acc[(g*4+0)*4+1] += wv4.x*tq.y;
        acc[(g*4+0)*4+2] += wv4.x*tq.z; acc[(g*4+0)*4+3] += wv4.x*tq.w;
        acc[(g*4+1)*4+0] += wv4.y*tq.x; acc[(g*4+1)*4+1] += wv4.y*tq.y;
        acc[(g*4+1)*4+2] += wv4.y*tq.z; acc[(g*4+1)*4+3] += wv4.y*tq.w;
        acc[(g*4+2)*4+0] += wv4.z*tq.x; acc[(g*4+2)*4+1] += wv4.z*tq.y;
        acc[(g*4+2)*4+2] += wv4.z*tq.z; acc[(g*4+2)*4+3] += wv4.z*tq.w;
        acc[(g*4+3)*4+0] += wv4.w*tq.x; acc[(g*4+3)*4+1] += wv4.w*tq.y;
        acc[(g*4+3)*4+2] += wv4.w*tq.z; acc[(g*4+3)*4+3] += wv4.w*tq.w;
      }
    }
    // loop-top barrier of next iter orders phase-C reads vs next phase-B ts writes
  }

  // ---- epilogue: (optional exp) + coalesced float4 stores ----
  float* obase = out + (size_t)bp * COUT * HW + rt * 256 + p0c;
  #pragma unroll
  for (int jj = 0; jj < 16; ++jj) {
    float4 v = make_float4(acc[jj*4], acc[jj*4+1], acc[jj*4+2], acc[jj*4+3]);
    if (is_abs) { v.x = expf(v.x); v.y = expf(v.y); v.z = expf(v.z); v.w = expf(v.w); }
    *(float4*)(obase + (size_t)(o0 + jj) * HW) = v;
  }
}

extern "C" void kernel_launch(void* const* d_in, const int* in_sizes, int n_in,
                              void* d_out, int out_size, void* d_ws, size_t ws_size,
                              hipStream_t stream) {
  const float* x   = (const float*)d_in[0];
  const float* w1x = (const float*)d_in[1];
  const float* w1y = (const float*)d_in[2];
  const float* w2x = (const float*)d_in[3];
  const float* w2y = (const float*)d_in[4];
  float* out = (float*)d_out;
  float* wsn = (float*)d_ws;   // 8768 floats

  prep_weights<<<1, 256, 0, stream>>>(w1x, w1y, w2x, w2y, wsn);
  fused_conv<<<512, BLK, 0, stream>>>(x, w1x, w1y, w2x, w2y, wsn, out);
}